// Round 5
// baseline (165.675 us; speedup 1.0000x reference)
//
#include <hip/hip_runtime.h>
#include <math.h>

#define Vdim 13
#define HW 20480               // 128*160
#define UV 169
#define TRUNC 4
#define NPIX (8 * HW)          // 163840
#define PPB 64                 // pixels per block
#define NPL 43                 // planes per thread: groups 43,43,43,40(+3 pad)

// Single-pass, register-resident: 4 threads/pixel (lane = 16 pixels x 4
// plane-groups), each thread holds 43 plane values in VGPRs. The empty
// asm "+v" pins force the allocator to keep them live (rounds 2/3 showed
// it otherwise rematerializes the loads -> two-pass). No LDS, no barrier;
// __launch_bounds__(256,4) => 128 VGPRs, 16 waves/CU.
__global__ __launch_bounds__(256, 4) void flow_regression_kernel(
    const float* __restrict__ x, float* __restrict__ out) {
    int t    = threadIdx.x;
    int wave = t >> 6;
    int lane = t & 63;
    int q    = lane >> 4;                 // plane group 0..3
    int pcol = (wave << 4) | (lane & 15); // local pixel 0..63
    int pix0 = blockIdx.x * PPB;          // HW%64==0 -> b uniform per block
    int b    = pix0 / HW;
    int hw   = pix0 - b * HW + pcol;
    int base_pl = q * NPL;                // 0,43,86,129

    const float* gp = x + (size_t)b * UV * HW + hw;

    // ---- Load my 43 planes (independent, coalesced: 4x64B per instr) ----
    float vals[NPL];
    #pragma unroll
    for (int i = 0; i < 40; ++i)
        vals[i] = gp[(size_t)(base_pl + i) * HW];
    #pragma unroll
    for (int i = 40; i < NPL; ++i) {      // only q==3 pads (planes 169..171)
        int pl   = base_pl + i;
        bool pad = pl >= UV;
        float v  = gp[(size_t)(pad ? (UV - 1) : pl) * HW];
        vals[i]  = pad ? -INFINITY : v;
    }
    // Pin: value now opaque -> load cannot be rematerialized later.
    #pragma unroll
    for (int i = 0; i < NPL; ++i) asm volatile("" : "+v"(vals[i]));

    // ---- Argmax (strict > => first index on ties, matches jnp.argmax) ----
    float m = vals[0];
    int  mi = base_pl;
    #pragma unroll
    for (int i = 1; i < NPL; ++i)
        if (vals[i] > m) { m = vals[i]; mi = base_pl + i; }
    {   // combine the 4 groups sharing a pixel; tie-break = smaller index
        float om = __shfl_xor(m, 16); int oi = __shfl_xor(mi, 16);
        if (om > m || (om == m && oi < mi)) { m = om; mi = oi; }
        om = __shfl_xor(m, 32); oi = __shfl_xor(mi, 32);
        if (om > m || (om == m && oi < mi)) { m = om; mi = oi; }
    }
    int ui = (mi * 158) >> 11;            // == mi/13 for mi in [0,169)
    int vi = mi - ui * Vdim;

    // ---- Masked exp sums, entirely from registers ----
    float s = 0.f, su = 0.f, sv = 0.f;
    int u = 3 * q, v = 4 * q;             // base_pl/13, base_pl%13
    #pragma unroll
    for (int i = 0; i < NPL; ++i) {
        bool in = (u - ui <= TRUNC) && (ui - u <= TRUNC) &&
                  (v - vi <= TRUNC) && (vi - v <= TRUNC);
        float e = in ? __expf(vals[i] - m) : 0.f;  // pad: exp(-inf-m)=0
        s  += e;
        su += e * (float)(u - 6);
        sv += e * (float)(v - 6);
        if (++v == Vdim) { v = 0; ++u; }
    }
    s  += __shfl_xor(s, 16);  su += __shfl_xor(su, 16);  sv += __shfl_xor(sv, 16);
    s  += __shfl_xor(s, 32);  su += __shfl_xor(su, 32);  sv += __shfl_xor(sv, 32);

    if (q == 0) {
        float inv = 1.0f / s;
        float* ob = out + (size_t)b * 2 * HW + hw;
        ob[0]  = su * inv;   // flowU
        ob[HW] = sv * inv;   // flowV
    }
}

extern "C" void kernel_launch(void* const* d_in, const int* in_sizes, int n_in,
                              void* d_out, int out_size, void* d_ws, size_t ws_size,
                              hipStream_t stream) {
    const float* x = (const float*)d_in[0];
    float* out = (float*)d_out;
    flow_regression_kernel<<<NPIX / PPB, 256, 0, stream>>>(x, out);
}